// Round 10
// baseline (208.434 us; speedup 1.0000x reference)
//
#include <hip/hip_runtime.h>
#include <hip/hip_bf16.h>

#define NEMB  4096
#define DIM   128
#define NROWS 32768
#define MARGIN 3.5e-4f   // >= 5x approx-error bound; validated r5-r8 (+1e-9 fold term)
#define RPB   128        // rows per block -> grid 256 = 1 block/CU
#define CHUNK 128        // codes per K-loop iteration
#define NITER 32         // NEMB/CHUNK
#define SCAN_REPS 2      // R18: deliberate scan double-execution (marginal-cost probe)

typedef _Float16 half8  __attribute__((ext_vector_type(8)));
typedef _Float16 half4v __attribute__((ext_vector_type(4)));
typedef _Float16 half2v __attribute__((ext_vector_type(2)));
typedef float    float16v __attribute__((ext_vector_type(16)));

typedef const __attribute__((address_space(1))) void* gas_ptr;
typedef __attribute__((address_space(3))) void*       las_ptr;

__device__ __forceinline__ void gload16(const void* g, void* l) {
    __builtin_amdgcn_global_load_lds((gas_ptr)g, (las_ptr)l, 16, 0, 0);
}

__device__ __forceinline__ half2v hmin2(half2v a, half2v b) {
    half2v r;
    r.x = (a.x < b.x) ? a.x : b.x;
    r.y = (a.y < b.y) ? a.y : b.y;
    return r;
}

// ---------------- K1: W -> fp16 (scale 2^16) fragment-major + ||w||^2 + swwh ----
__launch_bounds__(256)
__global__ void k_prep(const float* __restrict__ W, _Float16* __restrict__ Wh2,
                       float* __restrict__ sww, _Float16* __restrict__ swwh,
                       double* __restrict__ dsum, int* __restrict__ cnt) {
    const int b = blockIdx.x;               // 512 blocks, 8 rows each
    const int t = threadIdx.x;
    const int rbase = b * 8;

    if (b == 0 && t == 0) { *dsum = 0.0; *cnt = 0; }   // loss accumulators

    const int i4 = rbase * 32 + t;
    const float4 v = ((const float4*)W)[i4];
    const int r  = i4 >> 5;
    const int k0 = (i4 & 31) * 4;
    const int s  = r >> 5, cs = r & 31, c = k0 >> 4, h2 = (k0 >> 3) & 1, j0 = k0 & 7;
    half4v hv = { (_Float16)(v.x * 65536.0f), (_Float16)(v.y * 65536.0f),
                  (_Float16)(v.z * 65536.0f), (_Float16)(v.w * 65536.0f) };
    *(half4v*)(Wh2 + (s * 8 + c) * 512 + (h2 * 32 + cs) * 8 + j0) = hv;

    if (t < 64) {   // numpy-pairwise ||w||^2 (exact fp32 semantics, validated r3-r8)
        const int row = rbase + (t >> 3);
        const int j   = t & 7;
        const float* p = W + (size_t)row * DIM + j;
        float vv = p[0];
        float rr = __fmul_rn(vv, vv);
        #pragma unroll
        for (int q = 1; q < 16; ++q) { vv = p[q * 8]; rr = __fadd_rn(rr, __fmul_rn(vv, vv)); }
        float o = __shfl_xor(rr, 1, 64); rr = __fadd_rn(rr, o);
        o = __shfl_xor(rr, 2, 64); rr = __fadd_rn(rr, o);
        o = __shfl_xor(rr, 4, 64); rr = __fadd_rn(rr, o);
        if (j == 0) {
            sww[row]  = rr;
            swwh[row] = (_Float16)(rr * 32768.0f);   // sww*2^15, |err| ~ sww*2^-11
        }
    }
}

// ---------------- K2: R9 kernel with SCAN x2 (R18 marginal-cost measurement) ----------
// The scan (prologue DMA + 32-iteration loop) runs twice; gbuf rewrites are
// idempotent, so outputs are bit-identical.  dur_delta vs R9 = true scan cost S
// including all barrier/DMA stalls.  Rep-2 prologue DMA into buf0 is race-free:
// buf0's last reader (it=30 compute) is fenced by the it=31 top barrier.
__global__ __launch_bounds__(1024, 4)
void k_main(const float* __restrict__ x, const _Float16* __restrict__ Wh2,
            const float* __restrict__ W, const float* __restrict__ sww,
            const _Float16* __restrict__ swwh,
            float* __restrict__ out0, float* __restrict__ out1,
            float* __restrict__ out_idx, double* __restrict__ dsum,
            int* __restrict__ cnt, float* __restrict__ out_loss) {
    __shared__ __align__(16) _Float16 sA[2 * CHUNK * DIM];   // 64 KB dbuf / x-cache
    __shared__ _Float16 gbuf[RPB * 256];       // 64 KB group minima (swizzled)
    __shared__ float ssw[NEMB];                // 16 KB sww copy (refine only)
    __shared__ _Float16 swwh_lds[NEMB];        // 8 KB sww*2^15 fp16 (scan fold)
    __shared__ float red16[16];                // block loss partials

    const int tid  = threadIdx.x;
    const int wv   = tid >> 6;      // 0..15
    const int lane = tid & 63;
    const int l31  = lane & 31;
    const int h    = lane >> 5;
    const int r0   = blockIdx.x * RPB;
    const int mt   = wv & 3;        // 32-code slab within chunk
    const int np   = wv >> 2;       // ntile 0..3 (rows np*32..np*32+31)

    ((float4*)ssw)[tid] = ((const float4*)sww)[tid];
    if (tid < 512) ((float4*)swwh_lds)[tid] = ((const float4*)swwh)[tid];

    // B fragments: x rows of ntile np -> fp16 regs, B[n=lane&31][k=h*8+j] per 16-k chunk
    half8 bfr[8];
    {
        const float* xr = x + (size_t)(r0 + np * 32 + l31) * DIM + h * 8;
        #pragma unroll
        for (int c = 0; c < 8; ++c) {
            const float4 u0 = *(const float4*)(xr + c * 16);
            const float4 u1 = *(const float4*)(xr + c * 16 + 4);
            bfr[c] = (half8){ (_Float16)u0.x, (_Float16)u0.y, (_Float16)u0.z, (_Float16)u0.w,
                              (_Float16)u1.x, (_Float16)u1.y, (_Float16)u1.z, (_Float16)u1.w };
        }
    }

    // B_extra: B[row][k=0] = -1  (k=0 lives at h==0, j==0)
    half8 bx2 = (_Float16)0.0f;
    if (h == 0) bx2[0] = (_Float16)-1.0f;

    // sxx (numpy-pairwise exact) for this wave's 8 refine rows, kept in regs
    float sxx_reg;
    {
        const float* ps = x + (size_t)(r0 + wv * 8 + (lane >> 3)) * DIM + (lane & 7);
        float vv = ps[0];
        float rr = __fmul_rn(vv, vv);
        #pragma unroll
        for (int q = 1; q < 16; ++q) { vv = ps[q * 8]; rr = __fadd_rn(rr, __fmul_rn(vv, vv)); }
        float o = __shfl_xor(rr, 1, 64); rr = __fadd_rn(rr, o);
        o = __shfl_xor(rr, 2, 64); rr = __fadd_rn(rr, o);
        o = __shfl_xor(rr, 4, 64); rr = __fadd_rn(rr, o);
        sxx_reg = rr;
    }

    const int start = (blockIdx.x >> 3) & 31;

    for (int rep = 0; rep < SCAN_REPS; ++rep) {
        // prologue DMA: chunk `start` -> buffer 0
        {
            const char* src = (const char*)Wh2 + (size_t)start * (CHUNK * DIM * 2);
            #pragma unroll
            for (int r = 0; r < 2; ++r)
                gload16(src + wv * 2048 + r * 1024 + lane * 16, (char*)sA + wv * 2048 + r * 1024);
        }

        for (int it = 0; it < NITER; ++it) {
            __syncthreads();   // drains DMA issued one full iteration ago
            if (it + 1 < NITER) {
                const int nc = (start + it + 1) & (NITER - 1);
                const char* src = (const char*)Wh2 + (size_t)nc * (CHUNK * DIM * 2);
                char* dst = (char*)sA + ((it + 1) & 1) * (CHUNK * DIM * 2);
                #pragma unroll
                for (int r = 0; r < 2; ++r)
                    gload16(src + wv * 2048 + r * 1024 + lane * 16, dst + wv * 2048 + r * 1024);
            }
            const int cb = (start + it) & (NITER - 1);
            const int s  = cb * 4 + mt;   // global 32-code slab [0,128)

            // A_extra: A[code][k=0] = swwh[code]  (h==0, j==0 holds k=0)
            half8 ax = (_Float16)0.0f;
            if (h == 0) ax[0] = swwh_lds[s * 32 + l31];

            const _Float16* curb = sA + (it & 1) * (CHUNK * DIM);
            float16v acc;
            #pragma unroll
            for (int i = 0; i < 16; ++i) acc[i] = 0.f;

            #pragma unroll
            for (int c = 0; c < 8; ++c) {
                const half8 a = *(const half8*)(curb + (mt * 8 + c) * 512 + lane * 8);
                acc = __builtin_amdgcn_mfma_f32_32x32x16_f16(a, bfr[c], acc, 0, 0, 0);
            }
            // 9th MFMA: acc' = 2^16 x.w - 2^15 sww
            acc = __builtin_amdgcn_mfma_f32_32x32x16_f16(ax, bx2, acc, 0, 0, 0);

            // epilogue: group min = -2^-15 * max(acc'); max exact, scale exact
            const float mx0 = fmaxf(fmaxf(fmaxf(acc[0], acc[1]), fmaxf(acc[2], acc[3])),
                                    fmaxf(fmaxf(acc[4], acc[5]), fmaxf(acc[6], acc[7])));
            const float mx1 = fmaxf(fmaxf(fmaxf(acc[8], acc[9]), fmaxf(acc[10], acc[11])),
                                    fmaxf(fmaxf(acc[12], acc[13]), fmaxf(acc[14], acc[15])));
            const float g0 = mx0 * -0x1p-15f;
            const float g1 = mx1 * -0x1p-15f;
            union { half2v h2; int u; } cu, ot;
            cu.h2.x = (_Float16)g0; cu.h2.y = (_Float16)g1;   // groups 2s, 2s+1
            ot.u = __shfl_xor(cu.u, 32, 64);
            cu.h2 = hmin2(cu.h2, ot.h2);
            if (h == 0) {
                const int row = np * 32 + l31;                // local row
                const int ws  = (s + row) & 127;              // swizzled word slot
                ((int*)gbuf)[row * 128 + ws] = cu.u;
            }
        }
        // rep boundary: all waves' last buf0 read (it=30) fenced by it=31 barrier;
        // next rep's prologue overwrites buf0 only.
    }

    __syncthreads();   // scan complete; sA (DMA buffer) now dead

    // ---- refill sA with the block's x rows (64 KB fp32, coalesced) ----
    {
        float4* sAf4 = (float4*)sA;
        const float4* xg4 = (const float4*)(x + (size_t)r0 * DIM);
        #pragma unroll
        for (int i = 0; i < 4; ++i) sAf4[tid + i * 1024] = xg4[tid + i * 1024];
    }
    __syncthreads();
    const float* sAf = (const float*)sA;

    // ---- fused flag + exact refine (R9 form; x served from LDS) ----
    const int cig = lane >> 2;
    const int kp  = lane & 3;
    float p_acc = 0.f;
    for (int t = 0; t < 8; ++t) {
        const int lr  = wv * 8 + t;
        const int row = r0 + lr;

        const int2 gw = *(const int2*)((const char*)gbuf + lr * 512 + lane * 8);
        union { half2v h2; int u; } pa, pb;
        pa.u = gw.x; pb.u = gw.y;
        const float v0 = (float)pa.h2.x, v1 = (float)pa.h2.y;
        const float v2 = (float)pb.h2.x, v3 = (float)pb.h2.y;
        float m = fminf(fminf(v0, v1), fminf(v2, v3));
        #pragma unroll
        for (int off = 1; off < 64; off <<= 1) m = fminf(m, __shfl_xor(m, off, 64));
        const float thr = m + MARGIN;
        unsigned long long bal[4];
        bal[0] = __ballot(v0 <= thr);
        bal[1] = __ballot(v1 <= thr);
        bal[2] = __ballot(v2 <= thr);
        bal[3] = __ballot(v3 <= thr);

        const float sxr = __shfl(sxx_reg, t * 8, 64);
        const float* xl = sAf + lr * DIM;    // this row's x, in LDS

        // hoisted x quarter (from LDS; 16-lane same-address -> broadcast)
        float4 xv[8];
        {
            const float4* xq4 = (const float4*)(xl + kp * 32);
            #pragma unroll
            for (int j2 = 0; j2 < 8; ++j2) xv[j2] = xq4[j2];
        }

        float bv = 3.0e38f;
        int   bi = 0x7fffffff;

        #pragma unroll
        for (int j = 0; j < 4; ++j) {
            unsigned long long msk = bal[j];
            while (msk) {
                const int l = __builtin_ctzll(msk);
                msk &= msk - 1;
                const int wsl = 2 * l + (j >> 1);
                const int g   = 2 * ((wsl - lr) & 127) + (j & 1);
                const int c   = g * 16 + cig;
                const float4* wq4 = (const float4*)(W + (size_t)c * DIM + kp * 32);
                float dot = 0.f;
                #pragma unroll
                for (int j2 = 0; j2 < 8; ++j2) {
                    const float4 wv4 = wq4[j2];
                    dot = fmaf(xv[j2].x, wv4.x, dot);
                    dot = fmaf(xv[j2].y, wv4.y, dot);
                    dot = fmaf(xv[j2].z, wv4.z, dot);
                    dot = fmaf(xv[j2].w, wv4.w, dot);
                }
                float o = __shfl_xor(dot, 1, 64); dot = __fadd_rn(dot, o);
                o = __shfl_xor(dot, 2, 64); dot = __fadd_rn(dot, o);
                const float A = __fadd_rn(sxr, ssw[c]);
                const float d = __fsub_rn(A, __fmul_rn(2.0f, dot));
                if (d < bv || (d == bv && c < bi)) { bv = d; bi = c; }
            }
        }
        #pragma unroll
        for (int off = 1; off < 64; off <<= 1) {
            const float ov = __shfl_xor(bv, off, 64);
            const int   oi = __shfl_xor(bi, off, 64);
            if (ov < bv || (ov == bv && oi < bi)) { bv = ov; bi = oi; }
        }

        const float2 wv2 = *(const float2*)(W + (size_t)bi * DIM + lane * 2);
        const float2 xv2 = *(const float2*)(xl + lane * 2);
        const float d0 = wv2.x - xv2.x, d1 = wv2.y - xv2.y;
        const float p = fmaf(d0, d0, d1 * d1);
        *(float2*)(out0 + (size_t)row * DIM + lane * 2) = wv2;
        *(float2*)(out1 + (size_t)row * DIM + lane * 2) = wv2;
        p_acc = __fadd_rn(p_acc, p);
        if (lane == 0) out_idx[row] = (float)bi;
    }
    // wave partial -> block partial -> global double accumulate (loss)
    #pragma unroll
    for (int off = 32; off > 0; off >>= 1) p_acc += __shfl_down(p_acc, off, 64);
    if (lane == 0) red16[wv] = p_acc;
    __syncthreads();
    if (tid < 16) {
        float sblk = red16[tid];
        sblk += __shfl_xor(sblk, 1, 64);
        sblk += __shfl_xor(sblk, 2, 64);
        sblk += __shfl_xor(sblk, 4, 64);
        sblk += __shfl_xor(sblk, 8, 64);
        if (tid == 0) {
            atomicAdd(dsum, (double)sblk);
            __threadfence();
            const int prev = atomicAdd(cnt, 1);
            if (prev == (int)gridDim.x - 1) {
                __threadfence();
                const double tot = atomicAdd(dsum, 0.0);   // read full sum
                out_loss[0] = (float)(tot * (1.25 / ((double)NROWS * (double)DIM)));
            }
        }
    }
}

extern "C" void kernel_launch(void* const* d_in, const int* in_sizes, int n_in,
                              void* d_out, int out_size, void* d_ws, size_t ws_size,
                              hipStream_t stream) {
    const float* x = (const float*)d_in[0];   // [32768,128]
    const float* W = (const float*)d_in[1];   // [4096,128]
    float* out = (float*)d_out;

    float* out_q2d  = out;
    float* out_qst  = out + (size_t)NROWS * DIM;
    float* out_loss = out + (size_t)2 * NROWS * DIM;
    float* out_idx  = out + (size_t)2 * NROWS * DIM + 1;

    // ws layout (floats): sww[0..4096) | dsum@4096 cnt@4098 | swwh@8192 (8KB) | Wh2@36864
    float* ws   = (float*)d_ws;
    float* sww  = ws;
    double* dsum = (double*)(ws + 4096);                // byte 16384, 8-aligned
    int*    cnt  = (int*)(ws + 4098);
    _Float16* swwh = (_Float16*)(ws + 8192);            // 4096 halfs
    _Float16* Wh2  = (_Float16*)(ws + 4096 + 32768);    // 4096*128 fp16, fragment-major

    k_prep<<<NEMB / 8, 256, 0, stream>>>(W, Wh2, sww, swwh, dsum, cnt);
    k_main<<<NROWS / RPB, 1024, 0, stream>>>(x, Wh2, W, sww, swwh,
                                             out_q2d, out_qst, out_idx,
                                             dsum, cnt, out_loss);
}

// Round 11
// 180.089 us; speedup vs baseline: 1.1574x; 1.1574x over previous
//
#include <hip/hip_runtime.h>
#include <hip/hip_bf16.h>

#define NEMB  4096
#define DIM   128
#define NROWS 32768
#define MARGIN 3.5e-4f   // >= 5x approx-error bound; validated r5-r8 (+1e-9 fold term)
#define RPB   128        // rows per block -> grid 256 = 1 block/CU
#define CHUNK 128        // codes per K-loop iteration
#define NITER 32         // NEMB/CHUNK

typedef _Float16 half8  __attribute__((ext_vector_type(8)));
typedef _Float16 half4v __attribute__((ext_vector_type(4)));
typedef _Float16 half2v __attribute__((ext_vector_type(2)));
typedef float    float16v __attribute__((ext_vector_type(16)));

typedef const __attribute__((address_space(1))) void* gas_ptr;
typedef __attribute__((address_space(3))) void*       las_ptr;

__device__ __forceinline__ void gload16(const void* g, void* l) {
    __builtin_amdgcn_global_load_lds((gas_ptr)g, (las_ptr)l, 16, 0, 0);
}

__device__ __forceinline__ half2v hmin2(half2v a, half2v b) {
    half2v r;
    r.x = (a.x < b.x) ? a.x : b.x;
    r.y = (a.y < b.y) ? a.y : b.y;
    return r;
}

// ---------------- K1: W -> fp16 (scale 2^16) fragment-major + ||w||^2 + swwh ----
__launch_bounds__(256)
__global__ void k_prep(const float* __restrict__ W, _Float16* __restrict__ Wh2,
                       float* __restrict__ sww, _Float16* __restrict__ swwh,
                       double* __restrict__ dsum, int* __restrict__ cnt) {
    const int b = blockIdx.x;               // 512 blocks, 8 rows each
    const int t = threadIdx.x;
    const int rbase = b * 8;

    if (b == 0 && t == 0) { *dsum = 0.0; *cnt = 0; }   // loss accumulators

    const int i4 = rbase * 32 + t;
    const float4 v = ((const float4*)W)[i4];
    const int r  = i4 >> 5;
    const int k0 = (i4 & 31) * 4;
    const int s  = r >> 5, cs = r & 31, c = k0 >> 4, h2 = (k0 >> 3) & 1, j0 = k0 & 7;
    half4v hv = { (_Float16)(v.x * 65536.0f), (_Float16)(v.y * 65536.0f),
                  (_Float16)(v.z * 65536.0f), (_Float16)(v.w * 65536.0f) };
    *(half4v*)(Wh2 + (s * 8 + c) * 512 + (h2 * 32 + cs) * 8 + j0) = hv;

    if (t < 64) {   // numpy-pairwise ||w||^2 (exact fp32 semantics, validated r3-r8)
        const int row = rbase + (t >> 3);
        const int j   = t & 7;
        const float* p = W + (size_t)row * DIM + j;
        float vv = p[0];
        float rr = __fmul_rn(vv, vv);
        #pragma unroll
        for (int q = 1; q < 16; ++q) { vv = p[q * 8]; rr = __fadd_rn(rr, __fmul_rn(vv, vv)); }
        float o = __shfl_xor(rr, 1, 64); rr = __fadd_rn(rr, o);
        o = __shfl_xor(rr, 2, 64); rr = __fadd_rn(rr, o);
        o = __shfl_xor(rr, 4, 64); rr = __fadd_rn(rr, o);
        if (j == 0) {
            sww[row]  = rr;
            swwh[row] = (_Float16)(rr * 32768.0f);   // sww*2^15, |err| ~ sww*2^-11
        }
    }
}

// ---------------- K2: R9 scan + 8-row-batched refine (R19) ----------
// Scan: unchanged (R8/R9 lineage, measured 36.5us marginal in R10).
// Refine: all latency legs batched 8-wide per wave -- gbuf reads (one wait),
// min-reduce / argmin shfl stages (8 independent chains per stage), and the
// output W[bi] gather (8 loads issued together).  Item-eval per-row, bit-exact.
__global__ __launch_bounds__(1024, 4)
void k_main(const float* __restrict__ x, const _Float16* __restrict__ Wh2,
            const float* __restrict__ W, const float* __restrict__ sww,
            const _Float16* __restrict__ swwh,
            float* __restrict__ out0, float* __restrict__ out1,
            float* __restrict__ out_idx, double* __restrict__ dsum,
            int* __restrict__ cnt, float* __restrict__ out_loss) {
    __shared__ __align__(16) _Float16 sA[2 * CHUNK * DIM];   // 64 KB dbuf / x-cache
    __shared__ _Float16 gbuf[RPB * 256];       // 64 KB group minima (swizzled)
    __shared__ float ssw[NEMB];                // 16 KB sww copy (refine only)
    __shared__ _Float16 swwh_lds[NEMB];        // 8 KB sww*2^15 fp16 (scan fold)
    __shared__ float red16[16];                // block loss partials

    const int tid  = threadIdx.x;
    const int wv   = tid >> 6;      // 0..15
    const int lane = tid & 63;
    const int l31  = lane & 31;
    const int h    = lane >> 5;
    const int r0   = blockIdx.x * RPB;
    const int mt   = wv & 3;        // 32-code slab within chunk
    const int np   = wv >> 2;       // ntile 0..3 (rows np*32..np*32+31)

    ((float4*)ssw)[tid] = ((const float4*)sww)[tid];
    if (tid < 512) ((float4*)swwh_lds)[tid] = ((const float4*)swwh)[tid];

    // B fragments: x rows of ntile np -> fp16 regs, B[n=lane&31][k=h*8+j] per 16-k chunk
    half8 bfr[8];
    {
        const float* xr = x + (size_t)(r0 + np * 32 + l31) * DIM + h * 8;
        #pragma unroll
        for (int c = 0; c < 8; ++c) {
            const float4 u0 = *(const float4*)(xr + c * 16);
            const float4 u1 = *(const float4*)(xr + c * 16 + 4);
            bfr[c] = (half8){ (_Float16)u0.x, (_Float16)u0.y, (_Float16)u0.z, (_Float16)u0.w,
                              (_Float16)u1.x, (_Float16)u1.y, (_Float16)u1.z, (_Float16)u1.w };
        }
    }

    // B_extra: B[row][k=0] = -1  (k=0 lives at h==0, j==0)
    half8 bx2 = (_Float16)0.0f;
    if (h == 0) bx2[0] = (_Float16)-1.0f;

    // sxx (numpy-pairwise exact) for this wave's 8 refine rows, kept in regs
    float sxx_reg;
    {
        const float* ps = x + (size_t)(r0 + wv * 8 + (lane >> 3)) * DIM + (lane & 7);
        float vv = ps[0];
        float rr = __fmul_rn(vv, vv);
        #pragma unroll
        for (int q = 1; q < 16; ++q) { vv = ps[q * 8]; rr = __fadd_rn(rr, __fmul_rn(vv, vv)); }
        float o = __shfl_xor(rr, 1, 64); rr = __fadd_rn(rr, o);
        o = __shfl_xor(rr, 2, 64); rr = __fadd_rn(rr, o);
        o = __shfl_xor(rr, 4, 64); rr = __fadd_rn(rr, o);
        sxx_reg = rr;
    }

    // prologue DMA: chunk `start` -> buffer 0
    const int start = (blockIdx.x >> 3) & 31;
    {
        const char* src = (const char*)Wh2 + (size_t)start * (CHUNK * DIM * 2);
        #pragma unroll
        for (int r = 0; r < 2; ++r)
            gload16(src + wv * 2048 + r * 1024 + lane * 16, (char*)sA + wv * 2048 + r * 1024);
    }

    for (int it = 0; it < NITER; ++it) {
        __syncthreads();   // drains DMA issued one full iteration ago
        if (it + 1 < NITER) {
            const int nc = (start + it + 1) & (NITER - 1);
            const char* src = (const char*)Wh2 + (size_t)nc * (CHUNK * DIM * 2);
            char* dst = (char*)sA + ((it + 1) & 1) * (CHUNK * DIM * 2);
            #pragma unroll
            for (int r = 0; r < 2; ++r)
                gload16(src + wv * 2048 + r * 1024 + lane * 16, dst + wv * 2048 + r * 1024);
        }
        const int cb = (start + it) & (NITER - 1);
        const int s  = cb * 4 + mt;   // global 32-code slab [0,128)

        // A_extra: A[code][k=0] = swwh[code]  (h==0, j==0 holds k=0)
        half8 ax = (_Float16)0.0f;
        if (h == 0) ax[0] = swwh_lds[s * 32 + l31];

        const _Float16* curb = sA + (it & 1) * (CHUNK * DIM);
        float16v acc;
        #pragma unroll
        for (int i = 0; i < 16; ++i) acc[i] = 0.f;

        #pragma unroll
        for (int c = 0; c < 8; ++c) {
            const half8 a = *(const half8*)(curb + (mt * 8 + c) * 512 + lane * 8);
            acc = __builtin_amdgcn_mfma_f32_32x32x16_f16(a, bfr[c], acc, 0, 0, 0);
        }
        // 9th MFMA: acc' = 2^16 x.w - 2^15 sww
        acc = __builtin_amdgcn_mfma_f32_32x32x16_f16(ax, bx2, acc, 0, 0, 0);

        // epilogue: group min = -2^-15 * max(acc'); max exact, scale exact
        const float mx0 = fmaxf(fmaxf(fmaxf(acc[0], acc[1]), fmaxf(acc[2], acc[3])),
                                fmaxf(fmaxf(acc[4], acc[5]), fmaxf(acc[6], acc[7])));
        const float mx1 = fmaxf(fmaxf(fmaxf(acc[8], acc[9]), fmaxf(acc[10], acc[11])),
                                fmaxf(fmaxf(acc[12], acc[13]), fmaxf(acc[14], acc[15])));
        const float g0 = mx0 * -0x1p-15f;
        const float g1 = mx1 * -0x1p-15f;
        union { half2v h2; int u; } cu, ot;
        cu.h2.x = (_Float16)g0; cu.h2.y = (_Float16)g1;   // groups 2s, 2s+1
        ot.u = __shfl_xor(cu.u, 32, 64);
        cu.h2 = hmin2(cu.h2, ot.h2);
        if (h == 0) {
            const int row = np * 32 + l31;                // local row
            const int ws  = (s + row) & 127;              // swizzled word slot
            ((int*)gbuf)[row * 128 + ws] = cu.u;
        }
    }

    __syncthreads();   // scan complete; sA (DMA buffer) now dead

    // ---- refill sA with the block's x rows (64 KB fp32, coalesced) ----
    {
        float4* sAf4 = (float4*)sA;
        const float4* xg4 = (const float4*)(x + (size_t)r0 * DIM);
        #pragma unroll
        for (int i = 0; i < 4; ++i) sAf4[tid + i * 1024] = xg4[tid + i * 1024];
    }
    __syncthreads();
    const float* sAf = (const float*)sA;

    // ---- R19: fused flag + exact refine, 8-row batched latency legs ----
    const int cig = lane >> 2;
    const int kp  = lane & 3;

    // batched gbuf reads (8 ds_read_b64, one wait)
    int2 gw[8];
    #pragma unroll
    for (int t = 0; t < 8; ++t)
        gw[t] = *(const int2*)((const char*)gbuf + (wv * 8 + t) * 512 + lane * 8);

    // batched unpack + local min4
    float m_[8];
    #pragma unroll
    for (int t = 0; t < 8; ++t) {
        union { half2v h2; int u; } pa, pb;
        pa.u = gw[t].x; pb.u = gw[t].y;
        m_[t] = fminf(fminf((float)pa.h2.x, (float)pa.h2.y),
                      fminf((float)pb.h2.x, (float)pb.h2.y));
    }
    // batched 6-stage min-reduce (8 independent chains per stage)
    #pragma unroll
    for (int off = 1; off < 64; off <<= 1) {
        #pragma unroll
        for (int t = 0; t < 8; ++t) m_[t] = fminf(m_[t], __shfl_xor(m_[t], off, 64));
    }
    // batched sxr
    float sxr[8];
    #pragma unroll
    for (int t = 0; t < 8; ++t) sxr[t] = __shfl(sxx_reg, t * 8, 64);

    float bv[8]; int bi[8];
    #pragma unroll
    for (int t = 0; t < 8; ++t) { bv[t] = 3.0e38f; bi[t] = 0x7fffffff; }

    // per-row item eval (bit-exact R9 arithmetic; rows independent -> compiler
    // free to overlap across t)
    #pragma unroll
    for (int t = 0; t < 8; ++t) {
        const int lr = wv * 8 + t;
        union { half2v h2; int u; } pa, pb;
        pa.u = gw[t].x; pb.u = gw[t].y;
        const float v0 = (float)pa.h2.x, v1 = (float)pa.h2.y;
        const float v2 = (float)pb.h2.x, v3 = (float)pb.h2.y;
        const float thr = m_[t] + MARGIN;
        unsigned long long bal[4];
        bal[0] = __ballot(v0 <= thr);
        bal[1] = __ballot(v1 <= thr);
        bal[2] = __ballot(v2 <= thr);
        bal[3] = __ballot(v3 <= thr);

        const float* xl = sAf + lr * DIM;    // this row's x, in LDS
        float4 xv[8];
        {
            const float4* xq4 = (const float4*)(xl + kp * 32);
            #pragma unroll
            for (int j2 = 0; j2 < 8; ++j2) xv[j2] = xq4[j2];
        }

        #pragma unroll
        for (int j = 0; j < 4; ++j) {
            unsigned long long msk = bal[j];
            while (msk) {
                const int l = __builtin_ctzll(msk);
                msk &= msk - 1;
                const int wsl = 2 * l + (j >> 1);
                const int g   = 2 * ((wsl - lr) & 127) + (j & 1);
                const int c   = g * 16 + cig;
                const float4* wq4 = (const float4*)(W + (size_t)c * DIM + kp * 32);
                float dot = 0.f;
                #pragma unroll
                for (int j2 = 0; j2 < 8; ++j2) {
                    const float4 wv4 = wq4[j2];
                    dot = fmaf(xv[j2].x, wv4.x, dot);
                    dot = fmaf(xv[j2].y, wv4.y, dot);
                    dot = fmaf(xv[j2].z, wv4.z, dot);
                    dot = fmaf(xv[j2].w, wv4.w, dot);
                }
                float o = __shfl_xor(dot, 1, 64); dot = __fadd_rn(dot, o);
                o = __shfl_xor(dot, 2, 64); dot = __fadd_rn(dot, o);
                const float A = __fadd_rn(sxr[t], ssw[c]);
                const float d = __fsub_rn(A, __fmul_rn(2.0f, dot));
                if (d < bv[t] || (d == bv[t] && c < bi[t])) { bv[t] = d; bi[t] = c; }
            }
        }
    }

    // batched 6-stage argmin (8 independent chains per stage)
    #pragma unroll
    for (int off = 1; off < 64; off <<= 1) {
        #pragma unroll
        for (int t = 0; t < 8; ++t) {
            const float ov = __shfl_xor(bv[t], off, 64);
            const int   oi = __shfl_xor(bi[t], off, 64);
            if (ov < bv[t] || (ov == bv[t] && oi < bi[t])) { bv[t] = ov; bi[t] = oi; }
        }
    }

    // batched output gather: all 8 W[bi] row loads issued together (one exposure)
    float2 wv2r[8];
    #pragma unroll
    for (int t = 0; t < 8; ++t)
        wv2r[t] = *(const float2*)(W + (size_t)bi[t] * DIM + lane * 2);

    float p_acc = 0.f;
    #pragma unroll
    for (int t = 0; t < 8; ++t) {
        const int lr  = wv * 8 + t;
        const int row = r0 + lr;
        const float* xl = sAf + lr * DIM;
        const float2 xv2 = *(const float2*)(xl + lane * 2);
        const float d0 = wv2r[t].x - xv2.x, d1 = wv2r[t].y - xv2.y;
        const float p = fmaf(d0, d0, d1 * d1);
        *(float2*)(out0 + (size_t)row * DIM + lane * 2) = wv2r[t];
        *(float2*)(out1 + (size_t)row * DIM + lane * 2) = wv2r[t];
        p_acc = __fadd_rn(p_acc, p);
        if (lane == 0) out_idx[row] = (float)bi[t];
    }
    // wave partial -> block partial -> global double accumulate (loss)
    #pragma unroll
    for (int off = 32; off > 0; off >>= 1) p_acc += __shfl_down(p_acc, off, 64);
    if (lane == 0) red16[wv] = p_acc;
    __syncthreads();
    if (tid < 16) {
        float sblk = red16[tid];
        sblk += __shfl_xor(sblk, 1, 64);
        sblk += __shfl_xor(sblk, 2, 64);
        sblk += __shfl_xor(sblk, 4, 64);
        sblk += __shfl_xor(sblk, 8, 64);
        if (tid == 0) {
            atomicAdd(dsum, (double)sblk);
            __threadfence();
            const int prev = atomicAdd(cnt, 1);
            if (prev == (int)gridDim.x - 1) {
                __threadfence();
                const double tot = atomicAdd(dsum, 0.0);   // read full sum
                out_loss[0] = (float)(tot * (1.25 / ((double)NROWS * (double)DIM)));
            }
        }
    }
}

extern "C" void kernel_launch(void* const* d_in, const int* in_sizes, int n_in,
                              void* d_out, int out_size, void* d_ws, size_t ws_size,
                              hipStream_t stream) {
    const float* x = (const float*)d_in[0];   // [32768,128]
    const float* W = (const float*)d_in[1];   // [4096,128]
    float* out = (float*)d_out;

    float* out_q2d  = out;
    float* out_qst  = out + (size_t)NROWS * DIM;
    float* out_loss = out + (size_t)2 * NROWS * DIM;
    float* out_idx  = out + (size_t)2 * NROWS * DIM + 1;

    // ws layout (floats): sww[0..4096) | dsum@4096 cnt@4098 | swwh@8192 (8KB) | Wh2@36864
    float* ws   = (float*)d_ws;
    float* sww  = ws;
    double* dsum = (double*)(ws + 4096);                // byte 16384, 8-aligned
    int*    cnt  = (int*)(ws + 4098);
    _Float16* swwh = (_Float16*)(ws + 8192);            // 4096 halfs
    _Float16* Wh2  = (_Float16*)(ws + 4096 + 32768);    // 4096*128 fp16, fragment-major

    k_prep<<<NEMB / 8, 256, 0, stream>>>(W, Wh2, sww, swwh, dsum, cnt);
    k_main<<<NROWS / RPB, 1024, 0, stream>>>(x, Wh2, W, sww, swwh,
                                             out_q2d, out_qst, out_idx,
                                             dsum, cnt, out_loss);
}

// Round 12
// 171.944 us; speedup vs baseline: 1.2122x; 1.0474x over previous
//
#include <hip/hip_runtime.h>
#include <hip/hip_bf16.h>

#define NEMB  4096
#define DIM   128
#define NROWS 32768
#define MARGIN 3.5e-4f   // >= 5x approx-error bound; validated r5-r8 (+1e-9 fold term)
#define RPB   128        // rows per block -> grid 256 = 1 block/CU
#define CHUNK 128        // codes per K-loop iteration
#define NITER 32         // NEMB/CHUNK

typedef _Float16 half8  __attribute__((ext_vector_type(8)));
typedef _Float16 half4v __attribute__((ext_vector_type(4)));
typedef _Float16 half2v __attribute__((ext_vector_type(2)));
typedef float    float16v __attribute__((ext_vector_type(16)));

typedef const __attribute__((address_space(1))) void* gas_ptr;
typedef __attribute__((address_space(3))) void*       las_ptr;

__device__ __forceinline__ void gload16(const void* g, void* l) {
    __builtin_amdgcn_global_load_lds((gas_ptr)g, (las_ptr)l, 16, 0, 0);
}

__device__ __forceinline__ half2v hmin2(half2v a, half2v b) {
    half2v r;
    r.x = (a.x < b.x) ? a.x : b.x;
    r.y = (a.y < b.y) ? a.y : b.y;
    return r;
}

// ---------------- K1: W -> fp16 (scale 2^16) fragment-major + ||w||^2 + swwh ----
__launch_bounds__(256)
__global__ void k_prep(const float* __restrict__ W, _Float16* __restrict__ Wh2,
                       float* __restrict__ sww, _Float16* __restrict__ swwh,
                       double* __restrict__ dsum, int* __restrict__ cnt) {
    const int b = blockIdx.x;               // 512 blocks, 8 rows each
    const int t = threadIdx.x;
    const int rbase = b * 8;

    if (b == 0 && t == 0) { *dsum = 0.0; *cnt = 0; }   // loss accumulators

    const int i4 = rbase * 32 + t;
    const float4 v = ((const float4*)W)[i4];
    const int r  = i4 >> 5;
    const int k0 = (i4 & 31) * 4;
    const int s  = r >> 5, cs = r & 31, c = k0 >> 4, h2 = (k0 >> 3) & 1, j0 = k0 & 7;
    half4v hv = { (_Float16)(v.x * 65536.0f), (_Float16)(v.y * 65536.0f),
                  (_Float16)(v.z * 65536.0f), (_Float16)(v.w * 65536.0f) };
    *(half4v*)(Wh2 + (s * 8 + c) * 512 + (h2 * 32 + cs) * 8 + j0) = hv;

    if (t < 64) {   // numpy-pairwise ||w||^2 (exact fp32 semantics, validated r3-r8)
        const int row = rbase + (t >> 3);
        const int j   = t & 7;
        const float* p = W + (size_t)row * DIM + j;
        float vv = p[0];
        float rr = __fmul_rn(vv, vv);
        #pragma unroll
        for (int q = 1; q < 16; ++q) { vv = p[q * 8]; rr = __fadd_rn(rr, __fmul_rn(vv, vv)); }
        float o = __shfl_xor(rr, 1, 64); rr = __fadd_rn(rr, o);
        o = __shfl_xor(rr, 2, 64); rr = __fadd_rn(rr, o);
        o = __shfl_xor(rr, 4, 64); rr = __fadd_rn(rr, o);
        if (j == 0) {
            sww[row]  = rr;
            swwh[row] = (_Float16)(rr * 32768.0f);   // sww*2^15, |err| ~ sww*2^-11
        }
    }
}

// ---------------- K2: R9 base + scan-VALU cuts (R20) ----------
// vs R9 (110.4us): (1) zero16 C-operand for the first MFMA -> kills 16
// per-iteration acc-init moves; (2) ax high regs zeroed once, only elem 0
// rewritten per iteration; (3) prologue DMA issued at kernel top so its L2
// latency hides under ssw/bfr/sxx staging.  Refine: R9 form, untouched
// (both batching attempts R7/R11 regressed).  Numerics bit-identical to R9.
__global__ __launch_bounds__(1024, 4)
void k_main(const float* __restrict__ x, const _Float16* __restrict__ Wh2,
            const float* __restrict__ W, const float* __restrict__ sww,
            const _Float16* __restrict__ swwh,
            float* __restrict__ out0, float* __restrict__ out1,
            float* __restrict__ out_idx, double* __restrict__ dsum,
            int* __restrict__ cnt, float* __restrict__ out_loss) {
    __shared__ __align__(16) _Float16 sA[2 * CHUNK * DIM];   // 64 KB dbuf / x-cache
    __shared__ _Float16 gbuf[RPB * 256];       // 64 KB group minima (swizzled)
    __shared__ float ssw[NEMB];                // 16 KB sww copy (refine only)
    __shared__ _Float16 swwh_lds[NEMB];        // 8 KB sww*2^15 fp16 (scan fold)
    __shared__ float red16[16];                // block loss partials

    const int tid  = threadIdx.x;
    const int wv   = tid >> 6;      // 0..15
    const int lane = tid & 63;
    const int l31  = lane & 31;
    const int h    = lane >> 5;
    const int r0   = blockIdx.x * RPB;
    const int mt   = wv & 3;        // 32-code slab within chunk
    const int np   = wv >> 2;       // ntile 0..3 (rows np*32..np*32+31)

    // (3) prologue DMA first: chunk `start` -> buffer 0; latency hides under staging
    const int start = (blockIdx.x >> 3) & 31;
    {
        const char* src = (const char*)Wh2 + (size_t)start * (CHUNK * DIM * 2);
        #pragma unroll
        for (int r = 0; r < 2; ++r)
            gload16(src + wv * 2048 + r * 1024 + lane * 16, (char*)sA + wv * 2048 + r * 1024);
    }

    ((float4*)ssw)[tid] = ((const float4*)sww)[tid];
    if (tid < 512) ((float4*)swwh_lds)[tid] = ((const float4*)swwh)[tid];

    // B fragments: x rows of ntile np -> fp16 regs, B[n=lane&31][k=h*8+j] per 16-k chunk
    half8 bfr[8];
    {
        const float* xr = x + (size_t)(r0 + np * 32 + l31) * DIM + h * 8;
        #pragma unroll
        for (int c = 0; c < 8; ++c) {
            const float4 u0 = *(const float4*)(xr + c * 16);
            const float4 u1 = *(const float4*)(xr + c * 16 + 4);
            bfr[c] = (half8){ (_Float16)u0.x, (_Float16)u0.y, (_Float16)u0.z, (_Float16)u0.w,
                              (_Float16)u1.x, (_Float16)u1.y, (_Float16)u1.z, (_Float16)u1.w };
        }
    }

    // B_extra: B[row][k=0] = -1  (k=0 lives at h==0, j==0)
    half8 bx2 = (_Float16)0.0f;
    if (h == 0) bx2[0] = (_Float16)-1.0f;

    // (1) loop-invariant zero accumulator (C operand of the first MFMA)
    float16v zero16;
    #pragma unroll
    for (int i = 0; i < 16; ++i) zero16[i] = 0.f;

    // (2) ax: high regs zeroed once; only element 0 rewritten per iteration
    half8 ax = (_Float16)0.0f;

    // sxx (numpy-pairwise exact) for this wave's 8 refine rows, kept in regs
    float sxx_reg;
    {
        const float* ps = x + (size_t)(r0 + wv * 8 + (lane >> 3)) * DIM + (lane & 7);
        float vv = ps[0];
        float rr = __fmul_rn(vv, vv);
        #pragma unroll
        for (int q = 1; q < 16; ++q) { vv = ps[q * 8]; rr = __fadd_rn(rr, __fmul_rn(vv, vv)); }
        float o = __shfl_xor(rr, 1, 64); rr = __fadd_rn(rr, o);
        o = __shfl_xor(rr, 2, 64); rr = __fadd_rn(rr, o);
        o = __shfl_xor(rr, 4, 64); rr = __fadd_rn(rr, o);
        sxx_reg = rr;
    }

    for (int it = 0; it < NITER; ++it) {
        __syncthreads();   // drains DMA issued one full iteration ago
        if (it + 1 < NITER) {
            const int nc = (start + it + 1) & (NITER - 1);
            const char* src = (const char*)Wh2 + (size_t)nc * (CHUNK * DIM * 2);
            char* dst = (char*)sA + ((it + 1) & 1) * (CHUNK * DIM * 2);
            #pragma unroll
            for (int r = 0; r < 2; ++r)
                gload16(src + wv * 2048 + r * 1024 + lane * 16, dst + wv * 2048 + r * 1024);
        }
        const int cb = (start + it) & (NITER - 1);
        const int s  = cb * 4 + mt;   // global 32-code slab [0,128)

        // A_extra elem 0: swwh[code] on h==0 lanes (other 7 halfs stay 0)
        ax[0] = (h == 0) ? swwh_lds[s * 32 + l31] : (_Float16)0.0f;

        const _Float16* curb = sA + (it & 1) * (CHUNK * DIM);

        // first MFMA consumes zero16 as C (no acc re-init), then accumulate
        float16v acc;
        {
            const half8 a0 = *(const half8*)(curb + (mt * 8 + 0) * 512 + lane * 8);
            acc = __builtin_amdgcn_mfma_f32_32x32x16_f16(a0, bfr[0], zero16, 0, 0, 0);
        }
        #pragma unroll
        for (int c = 1; c < 8; ++c) {
            const half8 a = *(const half8*)(curb + (mt * 8 + c) * 512 + lane * 8);
            acc = __builtin_amdgcn_mfma_f32_32x32x16_f16(a, bfr[c], acc, 0, 0, 0);
        }
        // 9th MFMA: acc' = 2^16 x.w - 2^15 sww
        acc = __builtin_amdgcn_mfma_f32_32x32x16_f16(ax, bx2, acc, 0, 0, 0);

        // epilogue: group min = -2^-15 * max(acc'); max exact, scale exact
        const float mx0 = fmaxf(fmaxf(fmaxf(acc[0], acc[1]), fmaxf(acc[2], acc[3])),
                                fmaxf(fmaxf(acc[4], acc[5]), fmaxf(acc[6], acc[7])));
        const float mx1 = fmaxf(fmaxf(fmaxf(acc[8], acc[9]), fmaxf(acc[10], acc[11])),
                                fmaxf(fmaxf(acc[12], acc[13]), fmaxf(acc[14], acc[15])));
        const float g0 = mx0 * -0x1p-15f;
        const float g1 = mx1 * -0x1p-15f;
        union { half2v h2; int u; } cu, ot;
        cu.h2.x = (_Float16)g0; cu.h2.y = (_Float16)g1;   // groups 2s, 2s+1
        ot.u = __shfl_xor(cu.u, 32, 64);
        cu.h2 = hmin2(cu.h2, ot.h2);
        if (h == 0) {
            const int row = np * 32 + l31;                // local row
            const int ws  = (s + row) & 127;              // swizzled word slot
            ((int*)gbuf)[row * 128 + ws] = cu.u;
        }
    }

    __syncthreads();   // scan complete; sA (DMA buffer) now dead

    // ---- refill sA with the block's x rows (64 KB fp32, coalesced) ----
    {
        float4* sAf4 = (float4*)sA;
        const float4* xg4 = (const float4*)(x + (size_t)r0 * DIM);
        #pragma unroll
        for (int i = 0; i < 4; ++i) sAf4[tid + i * 1024] = xg4[tid + i * 1024];
    }
    __syncthreads();
    const float* sAf = (const float*)sA;

    // ---- fused flag + exact refine (R9 form; x served from LDS) ----
    const int cig = lane >> 2;
    const int kp  = lane & 3;
    float p_acc = 0.f;
    for (int t = 0; t < 8; ++t) {
        const int lr  = wv * 8 + t;
        const int row = r0 + lr;

        const int2 gw = *(const int2*)((const char*)gbuf + lr * 512 + lane * 8);
        union { half2v h2; int u; } pa, pb;
        pa.u = gw.x; pb.u = gw.y;
        const float v0 = (float)pa.h2.x, v1 = (float)pa.h2.y;
        const float v2 = (float)pb.h2.x, v3 = (float)pb.h2.y;
        float m = fminf(fminf(v0, v1), fminf(v2, v3));
        #pragma unroll
        for (int off = 1; off < 64; off <<= 1) m = fminf(m, __shfl_xor(m, off, 64));
        const float thr = m + MARGIN;
        unsigned long long bal[4];
        bal[0] = __ballot(v0 <= thr);
        bal[1] = __ballot(v1 <= thr);
        bal[2] = __ballot(v2 <= thr);
        bal[3] = __ballot(v3 <= thr);

        const float sxr = __shfl(sxx_reg, t * 8, 64);
        const float* xl = sAf + lr * DIM;    // this row's x, in LDS

        // hoisted x quarter (from LDS; 16-lane same-address -> broadcast)
        float4 xv[8];
        {
            const float4* xq4 = (const float4*)(xl + kp * 32);
            #pragma unroll
            for (int j2 = 0; j2 < 8; ++j2) xv[j2] = xq4[j2];
        }

        float bv = 3.0e38f;
        int   bi = 0x7fffffff;

        #pragma unroll
        for (int j = 0; j < 4; ++j) {
            unsigned long long msk = bal[j];
            while (msk) {
                const int l = __builtin_ctzll(msk);
                msk &= msk - 1;
                const int wsl = 2 * l + (j >> 1);
                const int g   = 2 * ((wsl - lr) & 127) + (j & 1);
                const int c   = g * 16 + cig;
                const float4* wq4 = (const float4*)(W + (size_t)c * DIM + kp * 32);
                float dot = 0.f;
                #pragma unroll
                for (int j2 = 0; j2 < 8; ++j2) {
                    const float4 wv4 = wq4[j2];
                    dot = fmaf(xv[j2].x, wv4.x, dot);
                    dot = fmaf(xv[j2].y, wv4.y, dot);
                    dot = fmaf(xv[j2].z, wv4.z, dot);
                    dot = fmaf(xv[j2].w, wv4.w, dot);
                }
                float o = __shfl_xor(dot, 1, 64); dot = __fadd_rn(dot, o);
                o = __shfl_xor(dot, 2, 64); dot = __fadd_rn(dot, o);
                const float A = __fadd_rn(sxr, ssw[c]);
                const float d = __fsub_rn(A, __fmul_rn(2.0f, dot));
                if (d < bv || (d == bv && c < bi)) { bv = d; bi = c; }
            }
        }
        #pragma unroll
        for (int off = 1; off < 64; off <<= 1) {
            const float ov = __shfl_xor(bv, off, 64);
            const int   oi = __shfl_xor(bi, off, 64);
            if (ov < bv || (ov == bv && oi < bi)) { bv = ov; bi = oi; }
        }

        const float2 wv2 = *(const float2*)(W + (size_t)bi * DIM + lane * 2);
        const float2 xv2 = *(const float2*)(xl + lane * 2);
        const float d0 = wv2.x - xv2.x, d1 = wv2.y - xv2.y;
        const float p = fmaf(d0, d0, d1 * d1);
        *(float2*)(out0 + (size_t)row * DIM + lane * 2) = wv2;
        *(float2*)(out1 + (size_t)row * DIM + lane * 2) = wv2;
        p_acc = __fadd_rn(p_acc, p);
        if (lane == 0) out_idx[row] = (float)bi;
    }
    // wave partial -> block partial -> global double accumulate (loss)
    #pragma unroll
    for (int off = 32; off > 0; off >>= 1) p_acc += __shfl_down(p_acc, off, 64);
    if (lane == 0) red16[wv] = p_acc;
    __syncthreads();
    if (tid < 16) {
        float sblk = red16[tid];
        sblk += __shfl_xor(sblk, 1, 64);
        sblk += __shfl_xor(sblk, 2, 64);
        sblk += __shfl_xor(sblk, 4, 64);
        sblk += __shfl_xor(sblk, 8, 64);
        if (tid == 0) {
            atomicAdd(dsum, (double)sblk);
            __threadfence();
            const int prev = atomicAdd(cnt, 1);
            if (prev == (int)gridDim.x - 1) {
                __threadfence();
                const double tot = atomicAdd(dsum, 0.0);   // read full sum
                out_loss[0] = (float)(tot * (1.25 / ((double)NROWS * (double)DIM)));
            }
        }
    }
}

extern "C" void kernel_launch(void* const* d_in, const int* in_sizes, int n_in,
                              void* d_out, int out_size, void* d_ws, size_t ws_size,
                              hipStream_t stream) {
    const float* x = (const float*)d_in[0];   // [32768,128]
    const float* W = (const float*)d_in[1];   // [4096,128]
    float* out = (float*)d_out;

    float* out_q2d  = out;
    float* out_qst  = out + (size_t)NROWS * DIM;
    float* out_loss = out + (size_t)2 * NROWS * DIM;
    float* out_idx  = out + (size_t)2 * NROWS * DIM + 1;

    // ws layout (floats): sww[0..4096) | dsum@4096 cnt@4098 | swwh@8192 (8KB) | Wh2@36864
    float* ws   = (float*)d_ws;
    float* sww  = ws;
    double* dsum = (double*)(ws + 4096);                // byte 16384, 8-aligned
    int*    cnt  = (int*)(ws + 4098);
    _Float16* swwh = (_Float16*)(ws + 8192);            // 4096 halfs
    _Float16* Wh2  = (_Float16*)(ws + 4096 + 32768);    // 4096*128 fp16, fragment-major

    k_prep<<<NEMB / 8, 256, 0, stream>>>(W, Wh2, sww, swwh, dsum, cnt);
    k_main<<<NROWS / RPB, 1024, 0, stream>>>(x, Wh2, W, sww, swwh,
                                             out_q2d, out_qst, out_idx,
                                             dsum, cnt, out_loss);
}